// Round 5
// baseline (591.635 us; speedup 1.0000x reference)
//
#include <hip/hip_runtime.h>
#include <hip/hip_fp16.h>

// Problem: B=32, S=2048, D=1024, H=1024
//   qp = query@W2 [B,H]; keys = values@W1 [B,S,H]; scores = tanh(qp+keys)@v [B,S]
//   w = softmax(scores); ctx = w@values [B,D]. Outputs: ctx (32768) ++ w (65536).
//
// R8: k_scores keeps R7's 256x256/8-wave geometry (verified fragment math)
// but replaces the 2-barrier-per-K-step lockstep with the T3/T4 schedule:
// double-buffered LDS (128 KiB), staging for t+1 issued BEFORE compute of t,
// ONE raw s_barrier per K-step preceded by s_waitcnt vmcnt(8) lgkmcnt(0) --
// the 8 A-loads (tile t+2, reg-staged two-deep) stay in flight across the
// barrier. R7 post-mortem: 1 resident block + two vmcnt(0) drains/K-step =
// ~4.4x stall over the MFMA+LDS floor; this removes the drains.

typedef _Float16 v8h  __attribute__((ext_vector_type(8)));
typedef __fp16   v2hf __attribute__((ext_vector_type(2)));
typedef float    v4f  __attribute__((ext_vector_type(4)));

#define B_DIM 32
#define S_DIM 2048
#define D_DIM 1024
#define H_DIM 1024

// workspace layout (bytes) -- ~2.4 MiB
#define WS_W1T    0u                       // [H][D] fp16 = 2 MiB
#define WS_QP     2097152u                 // [B][H] fp32
#define WS_SCORES (WS_QP + 131072u)        // [B][S] fp32 (atomicAdd target)

// async global->LDS, 16B per lane; LDS dest = wave-uniform base + lane*16
__device__ __forceinline__ void gl_lds16(const _Float16* g, _Float16* l) {
    __builtin_amdgcn_global_load_lds(
        (const __attribute__((address_space(1))) void*)g,
        (__attribute__((address_space(3))) void*)l, 16, 0, 0);
}

// ---------------- K0: prep (small) ----------------
// blocks [0,256):   qp = query @ W2  (32 b x 8 hc, 2-way K-split per block)
// blocks [256,512): W1 [D,H] -> W1T [H,D] fp16
// blocks [512,544): zero scores
__global__ void k_prep(const float* __restrict__ W1, _Float16* __restrict__ w1t,
                       const float* __restrict__ query, const float* __restrict__ W2,
                       float* __restrict__ qp, float* __restrict__ scores) {
    __shared__ float smem[64 * 65];
    int bid = blockIdx.x, tid = threadIdx.x;
    if (bid < 256) {
        int b = bid >> 3, hc = bid & 7;
        #pragma unroll
        for (int i = 0; i < 4; ++i)
            smem[i * 256 + tid] = query[b * D_DIM + i * 256 + tid];
        __syncthreads();
        int hh = tid & 127, half = tid >> 7;
        int h = hc * 128 + hh;
        const float* w2p = W2 + (size_t)(half * 512) * H_DIM + h;
        float acc = 0.f;
        #pragma unroll 8
        for (int d = 0; d < 512; ++d)
            acc += smem[half * 512 + d] * w2p[(size_t)d * H_DIM];
        smem[1024 + tid] = acc;
        __syncthreads();
        if (tid < 128)
            qp[b * H_DIM + hc * 128 + tid] = smem[1024 + tid] + smem[1024 + 128 + tid];
    } else if (bid < 512) {
        int j = bid - 256;
        int h0 = (j & 15) * 64, d0 = (j >> 4) * 64;
        #pragma unroll
        for (int i = 0; i < 16; ++i) {
            int idx = i * 256 + tid;
            int dd = idx >> 6, hh = idx & 63;
            smem[dd * 65 + hh] = W1[(size_t)(d0 + dd) * H_DIM + h0 + hh];
        }
        __syncthreads();
        #pragma unroll
        for (int i = 0; i < 16; ++i) {
            int idx = i * 256 + tid;
            int hh = idx >> 6, dd = idx & 63;
            w1t[(size_t)(h0 + hh) * D_DIM + d0 + dd] = (_Float16)smem[dd * 65 + hh];
        }
    } else {
        int j = bid - 512;
        size_t o = (size_t)j * 2048 + tid * 8;
        *(v4f*)(scores + o)     = (v4f){0.f, 0.f, 0.f, 0.f};
        *(v4f*)(scores + o + 4) = (v4f){0.f, 0.f, 0.f, 0.f};
    }
}

// ---------------- K1: fused scores GEMM ----------------
// grid = 1024 blocks (XCD-chunk swizzled), 512 thr (2m x 4n waves)
// block tile 256(m) x 256(n), wave tile 128x64 (mt=8, nt=4), BK=64, 16 steps.
// Double-buffered LDS; 1 barrier per K-step; counted vmcnt(8) keeps the
// reg-staged A loads (tile t+2) in flight across the barrier.
__global__ __launch_bounds__(512, 2) void k_scores(
        const float* __restrict__ values, const _Float16* __restrict__ w1t,
        const float* __restrict__ qp, const float* __restrict__ v,
        float* __restrict__ scores) {
    __shared__ _Float16 As[2][256 * 64];   // 2 x 32 KiB (buf0 reused as s_scores in epilogue)
    __shared__ _Float16 Bs[2][256 * 64];   // 2 x 32 KiB

    int tid = threadIdx.x;
    int wid = tid >> 6, lane = tid & 63;
    int quad = lane >> 4, l15 = lane & 15;
    int wm = wid >> 2, wn = wid & 3;     // 2 x 4 wave grid

    // XCD-chunked bijective swizzle (1024 % 8 == 0): np-siblings adjacent ->
    // same XCD -> A-tile fp32 re-reads are L2 hits.
    int bid = blockIdx.x;
    int idx = (bid & 7) * 128 + (bid >> 3);
    int np  = idx & 3;
    int mtb = idx >> 2;          // 0..255
    int b   = mtb >> 3;          // 0..31
    int m0  = (mtb & 7) * 256;
    int n0  = np * 256;

    // ---- A staging geometry: 4 writes x (64 rows x 8 fp32-slots) ----
    int arow  = tid >> 3;        // 0..63
    int aslot = tid & 7;
    const float* abase = values + ((size_t)b * S_DIM + m0) * D_DIM;
    int a_row[4], a_off[4];
    #pragma unroll
    for (int i = 0; i < 4; ++i) {
        int row  = i * 64 + arow;
        a_row[i] = row;
        a_off[i] = row * 64 + (aslot ^ (row & 7)) * 8;   // swizzled LDS halves
    }

    // ---- B staging geometry (gl_lds: 4 issues x 8 waves x 8 rows) ----
    int srow = lane >> 3;
    int kg   = lane & 7;

    v4f acc[8][4];
    #pragma unroll
    for (int i = 0; i < 8; ++i)
        #pragma unroll
        for (int j = 0; j < 4; ++j) acc[i][j] = (v4f){0.f, 0.f, 0.f, 0.f};

    v4f ap[8];

    // ================= prologue: tile 0 into buf0, A(t=1) into regs ========
    #pragma unroll
    for (int i = 0; i < 4; ++i) {
        const float* p = abase + (size_t)a_row[i] * D_DIM + aslot * 8;
        ap[2 * i]     = *(const v4f*)p;
        ap[2 * i + 1] = *(const v4f*)(p + 4);
    }
    #pragma unroll
    for (int i = 0; i < 4; ++i) {        // cvt waits the loads (compiler-counted)
        union { v8h h; v2hf p[4]; } u;
        u.p[0] = __builtin_amdgcn_cvt_pkrtz(ap[2 * i][0], ap[2 * i][1]);
        u.p[1] = __builtin_amdgcn_cvt_pkrtz(ap[2 * i][2], ap[2 * i][3]);
        u.p[2] = __builtin_amdgcn_cvt_pkrtz(ap[2 * i + 1][0], ap[2 * i + 1][1]);
        u.p[3] = __builtin_amdgcn_cvt_pkrtz(ap[2 * i + 1][2], ap[2 * i + 1][3]);
        *(v8h*)(&As[0][a_off[i]]) = u.h;
    }
    #pragma unroll
    for (int i = 0; i < 4; ++i) {        // B tile 0
        int brow = i * 64 + wid * 8;
        int row  = brow + srow;
        int kgs  = kg ^ (row & 7);
        gl_lds16(w1t + (size_t)(n0 + row) * D_DIM + kgs * 8, &Bs[0][brow * 64]);
    }
    #pragma unroll
    for (int i = 0; i < 4; ++i) {        // A loads for tile 1 -> ap
        const float* p = abase + (size_t)a_row[i] * D_DIM + 64 + aslot * 8;
        ap[2 * i]     = *(const v4f*)p;
        ap[2 * i + 1] = *(const v4f*)(p + 4);
    }
    asm volatile("s_waitcnt vmcnt(8) lgkmcnt(0)" ::: "memory");
    __builtin_amdgcn_s_barrier();

    // ================= main loop: 1 barrier / K-step =======================
    for (int kt = 0; kt < 16; ++kt) {
        int cur = kt & 1;
        if (kt < 15) {
            // stage tile kt+1 into buf[cur^1]:
            // (a) cvt+ds_write A (data already in ap; compiler waits its loads)
            #pragma unroll
            for (int i = 0; i < 4; ++i) {
                union { v8h h; v2hf p[4]; } u;
                u.p[0] = __builtin_amdgcn_cvt_pkrtz(ap[2 * i][0], ap[2 * i][1]);
                u.p[1] = __builtin_amdgcn_cvt_pkrtz(ap[2 * i][2], ap[2 * i][3]);
                u.p[2] = __builtin_amdgcn_cvt_pkrtz(ap[2 * i + 1][0], ap[2 * i + 1][1]);
                u.p[3] = __builtin_amdgcn_cvt_pkrtz(ap[2 * i + 1][2], ap[2 * i + 1][3]);
                *(v8h*)(&As[cur ^ 1][a_off[i]]) = u.h;
            }
            // (b) B gl_lds for kt+1
            int k1 = (kt + 1) * 64;
            #pragma unroll
            for (int i = 0; i < 4; ++i) {
                int brow = i * 64 + wid * 8;
                int row  = brow + srow;
                int kgs  = kg ^ (row & 7);
                gl_lds16(w1t + (size_t)(n0 + row) * D_DIM + k1 + kgs * 8,
                         &Bs[cur ^ 1][brow * 64]);
            }
            // (c) A loads for kt+2 -> ap (stay in flight across the barrier)
            int k2 = ((kt + 2) & 15) * 64;
            #pragma unroll
            for (int i = 0; i < 4; ++i) {
                const float* p = abase + (size_t)a_row[i] * D_DIM + k2 + aslot * 8;
                ap[2 * i]     = *(const v4f*)p;
                ap[2 * i + 1] = *(const v4f*)(p + 4);
            }
            __builtin_amdgcn_sched_barrier(0);   // pin all staging before compute
        }

        // ---- compute tile kt from buf[cur] ----
        __builtin_amdgcn_s_setprio(1);
        #pragma unroll
        for (int kk = 0; kk < 2; ++kk) {
            v8h af[8], bf[4];
            #pragma unroll
            for (int mt = 0; mt < 8; ++mt) {
                int row = wm * 128 + mt * 16 + l15;
                int ph  = (kk * 4 + quad) ^ (row & 7);
                af[mt] = *(const v8h*)(&As[cur][row * 64 + ph * 8]);
            }
            #pragma unroll
            for (int nt = 0; nt < 4; ++nt) {
                int row = wn * 64 + nt * 16 + l15;
                int ph  = (kk * 4 + quad) ^ (row & 7);
                bf[nt] = *(const v8h*)(&Bs[cur][row * 64 + ph * 8]);
            }
            #pragma unroll
            for (int mt = 0; mt < 8; ++mt)
                #pragma unroll
                for (int nt = 0; nt < 4; ++nt)
                    acc[mt][nt] = __builtin_amdgcn_mfma_f32_16x16x32_f16(
                        af[mt], bf[nt], acc[mt][nt], 0, 0, 0);
        }
        __builtin_amdgcn_s_setprio(0);

        // single end-of-step sync: my ds_reads done (lgkmcnt), B gl_lds for
        // kt+1 done (vmcnt(8): the 8 newest = A loads for kt+2, still flying)
        asm volatile("s_waitcnt vmcnt(8) lgkmcnt(0)" ::: "memory");
        __builtin_amdgcn_s_barrier();
    }

    // ---- epilogue: scores = tanh(acc + qp) . v, reduced over n ----
    float qpv[4], vv[4];
    #pragma unroll
    for (int nt = 0; nt < 4; ++nt) {
        int ng = n0 + wn * 64 + nt * 16 + l15;
        qpv[nt] = qp[b * H_DIM + ng];
        vv[nt]  = v[ng];
    }

    float* s_scores = (float*)&As[0][0];   // K-loop done; barrier above protects
    if (tid < 256) s_scores[tid] = 0.f;
    __syncthreads();

    #pragma unroll
    for (int mt = 0; mt < 8; ++mt) {
        #pragma unroll
        for (int r = 0; r < 4; ++r) {
            float s = 0.f;
            #pragma unroll
            for (int nt = 0; nt < 4; ++nt) {
                float x = acc[mt][nt][r] + qpv[nt];
                float e = __expf(2.f * x);           // tanh(x) = 1 - 2/(e^{2x}+1)
                s += (1.f - 2.f / (e + 1.f)) * vv[nt];
            }
            s += __shfl_xor(s, 1);
            s += __shfl_xor(s, 2);
            s += __shfl_xor(s, 4);
            s += __shfl_xor(s, 8);
            if (l15 == 0)
                atomicAdd(&s_scores[wm * 128 + mt * 16 + quad * 4 + r], s);
        }
    }
    __syncthreads();
    if (tid < 256) atomicAdd(&scores[(size_t)b * S_DIM + m0 + tid], s_scores[tid]);
}

// ---------------- K2: fused softmax + context ----------------
// One block per batch row b (32 blocks x 1024 thr). Softmax exact (full wout);
// ctx over only weights > 1e-7 (winner-take-all; skipped mass <= 2048e-7 ->
// |ctx err| ~1e-3 << 8.2e-2 threshold). Reads values fp32 directly.
__global__ __launch_bounds__(1024) void k_finish(
        const float* __restrict__ scores, const float* __restrict__ values,
        float* __restrict__ wout, float* __restrict__ ctx) {
    __shared__ float s_w[2048];
    __shared__ int   s_idx[2048];
    __shared__ float red[16];
    __shared__ float s_bcast;
    __shared__ int   s_cnt;

    int b = blockIdx.x, tid = threadIdx.x;
    int lane = tid & 63, wid = tid >> 6;

    float s0 = scores[b * S_DIM + tid];
    float s1 = scores[b * S_DIM + 1024 + tid];

    float m = fmaxf(s0, s1);
    #pragma unroll
    for (int off = 1; off <= 32; off <<= 1) m = fmaxf(m, __shfl_xor(m, off));
    if (lane == 0) red[wid] = m;
    if (tid == 0) s_cnt = 0;
    __syncthreads();
    if (tid == 0) {
        float mm = red[0];
        #pragma unroll
        for (int i = 1; i < 16; ++i) mm = fmaxf(mm, red[i]);
        s_bcast = mm;
    }
    __syncthreads();
    float rowmax = s_bcast;

    float e0 = __expf(s0 - rowmax);
    float e1 = __expf(s1 - rowmax);
    float sum = e0 + e1;
    #pragma unroll
    for (int off = 1; off <= 32; off <<= 1) sum += __shfl_xor(sum, off);
    if (lane == 0) red[wid] = sum;
    __syncthreads();
    if (tid == 0) {
        float ss = red[0];
        #pragma unroll
        for (int i = 1; i < 16; ++i) ss += red[i];
        s_bcast = 1.f / ss;
    }
    __syncthreads();
    float inv = s_bcast;

    float w0 = e0 * inv, w1 = e1 * inv;
    wout[b * S_DIM + tid]        = w0;
    wout[b * S_DIM + 1024 + tid] = w1;
    s_w[tid]        = w0;
    s_w[tid + 1024] = w1;

    if (w0 > 1e-7f) { int p = atomicAdd(&s_cnt, 1); s_idx[p] = tid; }
    if (w1 > 1e-7f) { int p = atomicAdd(&s_cnt, 1); s_idx[p] = tid + 1024; }
    __syncthreads();
    int cnt = s_cnt;

    float acc = 0.f;
    const float* vb = values + (size_t)b * S_DIM * D_DIM + tid;
    for (int i = 0; i < cnt; ++i) {
        int s = s_idx[i];
        acc += s_w[s] * vb[(size_t)s * D_DIM];
    }
    ctx[b * D_DIM + tid] = acc;
}

extern "C" void kernel_launch(void* const* d_in, const int* in_sizes, int n_in,
                              void* d_out, int out_size, void* d_ws, size_t ws_size,
                              hipStream_t stream) {
    const float* query  = (const float*)d_in[0];
    const float* values = (const float*)d_in[1];
    const float* W1     = (const float*)d_in[2];
    const float* W2     = (const float*)d_in[3];
    const float* v      = (const float*)d_in[4];

    char* ws = (char*)d_ws;
    _Float16* w1t = (_Float16*)(ws + WS_W1T);
    float* qp     = (float*)(ws + WS_QP);
    float* scores = (float*)(ws + WS_SCORES);

    float* ctx  = (float*)d_out;            // [32, 1024]
    float* wout = (float*)d_out + 32768;    // [32, 2048]

    k_prep<<<dim3(544), 256, 0, stream>>>(W1, w1t, query, W2, qp, scores);
    k_scores<<<dim3(1024), 512, 0, stream>>>(values, w1t, qp, v, scores);
    k_finish<<<dim3(32), 1024, 0, stream>>>(scores, values, wout, ctx);
}

// Round 6
// 556.856 us; speedup vs baseline: 1.0625x; 1.0625x over previous
//
#include <hip/hip_runtime.h>
#include <hip/hip_fp16.h>

// Problem: B=32, S=2048, D=1024, H=1024
//   qp = query@W2 [B,H]; keys = values@W1 [B,S,H]; scores = tanh(qp+keys)@v [B,S]
//   w = softmax(scores); ctx = w@values [B,D]. Outputs: ctx (32768) ++ w (65536).
//
// R9: k_scores ported to the m201-style phase schedule. R8 post-mortem: the
// per-step cycle ledger (ds_read 2304 + MFMA 2483 + VALU 640 + ds_write 380
// ~= measured 10.4k cyc) shows NOTHING overlapped. Fix: (1) restore fp16
// values (v16) conversion in k_prep so BOTH operands stage via
// global_load_lds (no cvt/ds_write in the hot loop); (2) 4 sub-phases per
// K-tile: {ds_read 8; [gl_lds x4]; barrier; lgkmcnt(0)+sched_barrier;
// setprio(1); 16 MFMA; setprio(0)} -- LDS latency hides in barrier-wait,
// MFMA clusters run uninterrupted (learn_hip m201: 62% MfmaUtil on this
// exact geometry).

typedef _Float16 v8h  __attribute__((ext_vector_type(8)));
typedef float    v4f  __attribute__((ext_vector_type(4)));

#define B_DIM 32
#define S_DIM 2048
#define D_DIM 1024
#define H_DIM 1024

// workspace layout (bytes) -- ~130.5 MiB
#define WS_V16    0u                       // [B][S][D] fp16 = 128 MiB
#define WS_W1T    134217728u               // [H][D] fp16 = 2 MiB
#define WS_QP     (WS_W1T + 2097152u)      // [B][H] fp32
#define WS_SCORES (WS_QP + 131072u)        // [B][S] fp32 (atomicAdd target)

// async global->LDS, 16B per lane; LDS dest = wave-uniform base + lane*16
__device__ __forceinline__ void gl_lds16(const _Float16* g, _Float16* l) {
    __builtin_amdgcn_global_load_lds(
        (const __attribute__((address_space(1))) void*)g,
        (__attribute__((address_space(3))) void*)l, 16, 0, 0);
}

// ---------------- K0: prep ----------------
// blocks [0,256):     qp = query @ W2  (32 b x 8 hc, 2-way K-split per block)
// blocks [256,512):   W1 [D,H] -> W1T [H,D] fp16
// blocks [512,544):   zero scores
// blocks [544,33312): values fp32 -> fp16 (nontemporal reads)
__global__ void k_prep(const float* __restrict__ values, _Float16* __restrict__ v16,
                       const float* __restrict__ W1, _Float16* __restrict__ w1t,
                       const float* __restrict__ query, const float* __restrict__ W2,
                       float* __restrict__ qp, float* __restrict__ scores) {
    __shared__ float smem[64 * 65];
    int bid = blockIdx.x, tid = threadIdx.x;
    if (bid >= 544) {
        size_t i = ((size_t)(bid - 544) * 256 + tid) * 8;
        v4f f0 = __builtin_nontemporal_load((const v4f*)(values + i));
        v4f f1 = __builtin_nontemporal_load((const v4f*)(values + i + 4));
        v8h hv;
        hv[0] = (_Float16)f0[0]; hv[1] = (_Float16)f0[1];
        hv[2] = (_Float16)f0[2]; hv[3] = (_Float16)f0[3];
        hv[4] = (_Float16)f1[0]; hv[5] = (_Float16)f1[1];
        hv[6] = (_Float16)f1[2]; hv[7] = (_Float16)f1[3];
        *(v8h*)(v16 + i) = hv;
    } else if (bid < 256) {
        int b = bid >> 3, hc = bid & 7;
        #pragma unroll
        for (int i = 0; i < 4; ++i)
            smem[i * 256 + tid] = query[b * D_DIM + i * 256 + tid];
        __syncthreads();
        int hh = tid & 127, half = tid >> 7;
        int h = hc * 128 + hh;
        const float* w2p = W2 + (size_t)(half * 512) * H_DIM + h;
        float acc = 0.f;
        #pragma unroll 8
        for (int d = 0; d < 512; ++d)
            acc += smem[half * 512 + d] * w2p[(size_t)d * H_DIM];
        smem[1024 + tid] = acc;
        __syncthreads();
        if (tid < 128)
            qp[b * H_DIM + hc * 128 + tid] = smem[1024 + tid] + smem[1024 + 128 + tid];
    } else if (bid < 512) {
        int j = bid - 256;
        int h0 = (j & 15) * 64, d0 = (j >> 4) * 64;
        #pragma unroll
        for (int i = 0; i < 16; ++i) {
            int idx = i * 256 + tid;
            int dd = idx >> 6, hh = idx & 63;
            smem[dd * 65 + hh] = W1[(size_t)(d0 + dd) * H_DIM + h0 + hh];
        }
        __syncthreads();
        #pragma unroll
        for (int i = 0; i < 16; ++i) {
            int idx = i * 256 + tid;
            int hh = idx >> 6, dd = idx & 63;
            w1t[(size_t)(h0 + hh) * D_DIM + d0 + dd] = (_Float16)smem[dd * 65 + hh];
        }
    } else {
        int j = bid - 512;
        size_t o = (size_t)j * 2048 + tid * 8;
        *(v4f*)(scores + o)     = (v4f){0.f, 0.f, 0.f, 0.f};
        *(v4f*)(scores + o + 4) = (v4f){0.f, 0.f, 0.f, 0.f};
    }
}

// ---------------- K1: fused scores GEMM (phase-scheduled) ----------------
// grid = 1024 blocks (XCD-chunk swizzled), 512 thr (2m x 4n waves)
// block tile 256(m) x 256(n), wave tile 128x64 (mt=8, nt=4), BK=64, 16 steps.
// Both operands fp16 via global_load_lds into double-buffered swizzled LDS.
// 4 phases per K-step; prefetch for t+1 issued in phases 0-1; end-of-step
// vmcnt(0)+barrier (loads have >=2 phases of slack -> wait is ~free).

// one K-step: compute from CA/CB, prefetch tile (k1) into NA/NB if PF
template<bool PF>
__device__ __forceinline__ void gemm_step(
        const _Float16* CA, const _Float16* CB,
        _Float16* NA, _Float16* NB,
        const _Float16* a16, const _Float16* bw, int k1,
        int wm, int wn, int quad, int l15, int wid, int srow, int kg,
        v4f acc[8][4]) {
    #pragma unroll
    for (int kk = 0; kk < 2; ++kk) {
        v8h bf[4];
        #pragma unroll
        for (int j = 0; j < 4; ++j) {
            int row = wn * 64 + j * 16 + l15;
            int ph  = (kk * 4 + quad) ^ (row & 7);
            bf[j] = *(const v8h*)(&CB[row * 64 + ph * 8]);
        }
        #pragma unroll
        for (int mh = 0; mh < 2; ++mh) {
            v8h af[4];
            #pragma unroll
            for (int i = 0; i < 4; ++i) {
                int row = wm * 128 + mh * 64 + i * 16 + l15;
                int ph  = (kk * 4 + quad) ^ (row & 7);
                af[i] = *(const v8h*)(&CA[row * 64 + ph * 8]);
            }
            if (PF && kk == 0) {
                // phase 0: A prefetch (4 issues); phase 1: B prefetch (4)
                #pragma unroll
                for (int i = 0; i < 4; ++i) {
                    int brow = i * 64 + wid * 8;
                    int row  = brow + srow;
                    int kgs  = kg ^ (row & 7);
                    if (mh == 0)
                        gl_lds16(a16 + (size_t)row * D_DIM + k1 + kgs * 8,
                                 &NA[brow * 64]);
                    else
                        gl_lds16(bw + (size_t)row * D_DIM + k1 + kgs * 8,
                                 &NB[brow * 64]);
                }
            }
            __builtin_amdgcn_s_barrier();                 // reads finish here
            asm volatile("s_waitcnt lgkmcnt(0)" ::: "memory");
            __builtin_amdgcn_sched_barrier(0);            // rule 18
            __builtin_amdgcn_s_setprio(1);
            #pragma unroll
            for (int i = 0; i < 4; ++i)
                #pragma unroll
                for (int j = 0; j < 4; ++j)
                    acc[mh * 4 + i][j] = __builtin_amdgcn_mfma_f32_16x16x32_f16(
                        af[i], bf[j], acc[mh * 4 + i][j], 0, 0, 0);
            __builtin_amdgcn_s_setprio(0);
        }
    }
    // end-of-step: prefetch drained (>=2 phases of slack); bufs swappable
    if (PF) asm volatile("s_waitcnt vmcnt(0)" ::: "memory");
    __builtin_amdgcn_s_barrier();
}

__global__ __launch_bounds__(512, 2) void k_scores(
        const _Float16* __restrict__ v16, const _Float16* __restrict__ w1t,
        const float* __restrict__ qp, const float* __restrict__ v,
        float* __restrict__ scores) {
    __shared__ _Float16 As[2][256 * 64];   // 2 x 32 KiB (buf0 reused in epilogue)
    __shared__ _Float16 Bs[2][256 * 64];   // 2 x 32 KiB

    int tid = threadIdx.x;
    int wid = tid >> 6, lane = tid & 63;
    int quad = lane >> 4, l15 = lane & 15;
    int wm = wid >> 2, wn = wid & 3;     // 2 x 4 wave grid

    // XCD-chunked bijective swizzle (1024 % 8 == 0): np-siblings adjacent ->
    // same XCD -> A-tile re-reads are L2 hits.
    int bid = blockIdx.x;
    int idx = (bid & 7) * 128 + (bid >> 3);
    int np  = idx & 3;
    int mtb = idx >> 2;          // 0..255
    int b   = mtb >> 3;          // 0..31
    int m0  = (mtb & 7) * 256;
    int n0  = np * 256;

    // staging geometry: issue i covers rows i*64 + wid*8 + srow, 8 lanes/row
    int srow = lane >> 3;
    int kg   = lane & 7;
    const _Float16* a16 = v16 + ((size_t)b * S_DIM + m0) * D_DIM;
    const _Float16* bw  = w1t + (size_t)n0 * D_DIM;

    v4f acc[8][4];
    #pragma unroll
    for (int i = 0; i < 8; ++i)
        #pragma unroll
        for (int j = 0; j < 4; ++j) acc[i][j] = (v4f){0.f, 0.f, 0.f, 0.f};

    // ---- prologue: stage tile 0 into buf0 ----
    #pragma unroll
    for (int i = 0; i < 4; ++i) {
        int brow = i * 64 + wid * 8;
        int row  = brow + srow;
        int kgs  = kg ^ (row & 7);
        gl_lds16(a16 + (size_t)row * D_DIM + kgs * 8, &As[0][brow * 64]);
        gl_lds16(bw  + (size_t)row * D_DIM + kgs * 8, &Bs[0][brow * 64]);
    }
    asm volatile("s_waitcnt vmcnt(0)" ::: "memory");
    __builtin_amdgcn_s_barrier();

    // ---- 16 K-steps; last one without prefetch ----
    for (int t = 0; t < 15; ++t) {
        int cur = t & 1;
        gemm_step<true>(As[cur], Bs[cur], As[cur ^ 1], Bs[cur ^ 1],
                        a16, bw, (t + 1) * 64,
                        wm, wn, quad, l15, wid, srow, kg, acc);
    }
    gemm_step<false>(As[1], Bs[1], As[0], Bs[0], a16, bw, 0,
                     wm, wn, quad, l15, wid, srow, kg, acc);

    // ---- epilogue: scores = tanh(acc + qp) . v, reduced over n ----
    float qpv[4], vv[4];
    #pragma unroll
    for (int nt = 0; nt < 4; ++nt) {
        int ng = n0 + wn * 64 + nt * 16 + l15;
        qpv[nt] = qp[b * H_DIM + ng];
        vv[nt]  = v[ng];
    }

    float* s_scores = (float*)&As[0][0];   // K-loop done; final barrier protects
    if (tid < 256) s_scores[tid] = 0.f;
    __syncthreads();

    #pragma unroll
    for (int mt = 0; mt < 8; ++mt) {
        #pragma unroll
        for (int r = 0; r < 4; ++r) {
            float s = 0.f;
            #pragma unroll
            for (int nt = 0; nt < 4; ++nt) {
                float x = acc[mt][nt][r] + qpv[nt];
                float e = __expf(2.f * x);           // tanh(x) = 1 - 2/(e^{2x}+1)
                s += (1.f - 2.f / (e + 1.f)) * vv[nt];
            }
            s += __shfl_xor(s, 1);
            s += __shfl_xor(s, 2);
            s += __shfl_xor(s, 4);
            s += __shfl_xor(s, 8);
            if (l15 == 0)
                atomicAdd(&s_scores[wm * 128 + mt * 16 + quad * 4 + r], s);
        }
    }
    __syncthreads();
    if (tid < 256) atomicAdd(&scores[(size_t)b * S_DIM + m0 + tid], s_scores[tid]);
}

// ---------------- K2: fused softmax + context ----------------
// One block per batch row b (32 blocks x 1024 thr). Softmax exact (full wout);
// ctx over only weights > 1e-7 (winner-take-all; skipped mass <= 2048e-7 ->
// |ctx err| ~1e-3 << 8.2e-2 threshold). Reads values fp32 directly.
__global__ __launch_bounds__(1024) void k_finish(
        const float* __restrict__ scores, const float* __restrict__ values,
        float* __restrict__ wout, float* __restrict__ ctx) {
    __shared__ float s_w[2048];
    __shared__ int   s_idx[2048];
    __shared__ float red[16];
    __shared__ float s_bcast;
    __shared__ int   s_cnt;

    int b = blockIdx.x, tid = threadIdx.x;
    int lane = tid & 63, wid = tid >> 6;

    float s0 = scores[b * S_DIM + tid];
    float s1 = scores[b * S_DIM + 1024 + tid];

    float m = fmaxf(s0, s1);
    #pragma unroll
    for (int off = 1; off <= 32; off <<= 1) m = fmaxf(m, __shfl_xor(m, off));
    if (lane == 0) red[wid] = m;
    if (tid == 0) s_cnt = 0;
    __syncthreads();
    if (tid == 0) {
        float mm = red[0];
        #pragma unroll
        for (int i = 1; i < 16; ++i) mm = fmaxf(mm, red[i]);
        s_bcast = mm;
    }
    __syncthreads();
    float rowmax = s_bcast;

    float e0 = __expf(s0 - rowmax);
    float e1 = __expf(s1 - rowmax);
    float sum = e0 + e1;
    #pragma unroll
    for (int off = 1; off <= 32; off <<= 1) sum += __shfl_xor(sum, off);
    if (lane == 0) red[wid] = sum;
    __syncthreads();
    if (tid == 0) {
        float ss = red[0];
        #pragma unroll
        for (int i = 1; i < 16; ++i) ss += red[i];
        s_bcast = 1.f / ss;
    }
    __syncthreads();
    float inv = s_bcast;

    float w0 = e0 * inv, w1 = e1 * inv;
    wout[b * S_DIM + tid]        = w0;
    wout[b * S_DIM + 1024 + tid] = w1;
    s_w[tid]        = w0;
    s_w[tid + 1024] = w1;

    if (w0 > 1e-7f) { int p = atomicAdd(&s_cnt, 1); s_idx[p] = tid; }
    if (w1 > 1e-7f) { int p = atomicAdd(&s_cnt, 1); s_idx[p] = tid + 1024; }
    __syncthreads();
    int cnt = s_cnt;

    float acc = 0.f;
    const float* vb = values + (size_t)b * S_DIM * D_DIM + tid;
    for (int i = 0; i < cnt; ++i) {
        int s = s_idx[i];
        acc += s_w[s] * vb[(size_t)s * D_DIM];
    }
    ctx[b * D_DIM + tid] = acc;
}

extern "C" void kernel_launch(void* const* d_in, const int* in_sizes, int n_in,
                              void* d_out, int out_size, void* d_ws, size_t ws_size,
                              hipStream_t stream) {
    const float* query  = (const float*)d_in[0];
    const float* values = (const float*)d_in[1];
    const float* W1     = (const float*)d_in[2];
    const float* W2     = (const float*)d_in[3];
    const float* v      = (const float*)d_in[4];

    char* ws = (char*)d_ws;
    _Float16* v16 = (_Float16*)(ws + WS_V16);
    _Float16* w1t = (_Float16*)(ws + WS_W1T);
    float* qp     = (float*)(ws + WS_QP);
    float* scores = (float*)(ws + WS_SCORES);

    float* ctx  = (float*)d_out;            // [32, 1024]
    float* wout = (float*)d_out + 32768;    // [32, 2048]

    k_prep<<<dim3(33312), 256, 0, stream>>>(values, v16, W1, w1t, query, W2, qp, scores);
    k_scores<<<dim3(1024), 512, 0, stream>>>(v16, w1t, qp, v, scores);
    k_finish<<<dim3(32), 1024, 0, stream>>>(scores, values, wout, ctx);
}